// Round 2
// baseline (303.250 us; speedup 1.0000x reference)
//
#include <hip/hip_runtime.h>

// SioConvPS: z/dt/g projections (bf16 MFMA GEMM) -> stable linear scan
// h_t = sig(z)sig(dt) + sig(-dt) h_{t-1}  (chunked 3-pass) -> gated y GEMM.
// Outputs (f32): d_out = [y (B,L,D), h (B,L,D)].

#define BDIM 4
#define LDIM 4096
#define DDIM 1024
#define MROWS (BDIM * LDIM)   // 16384
#define KDIM 1024
#define NPROJ 3072
#define NCHUNK 64             // chunks along L
#define LCHUNK 64             // LDIM / NCHUNK

typedef __attribute__((ext_vector_type(8))) short short8v;
typedef __attribute__((ext_vector_type(4))) float f32x4;

__device__ __forceinline__ float bf2f(short u) {
    union { float f; unsigned int i; } v;
    v.i = ((unsigned int)(unsigned short)u) << 16;
    return v.f;
}
__device__ __forceinline__ short f2bf(float f) {
    union { float f; unsigned int i; } v; v.f = f;
    unsigned int r = v.i + 0x7FFFu + ((v.i >> 16) & 1u);  // RNE
    return (short)(r >> 16);
}
__device__ __forceinline__ float sigf(float x) { return 1.f / (1.f + __expf(-x)); }

// ---------------- cast f32 -> bf16, vectorized ----------------
__global__ void cast_f32_bf16(const float* __restrict__ src, short* __restrict__ dst, int n4) {
    int i = blockIdx.x * blockDim.x + threadIdx.x;
    int stride = gridDim.x * blockDim.x;
    for (; i < n4; i += stride) {
        float4 v = reinterpret_cast<const float4*>(src)[i];
        short4 o;
        o.x = f2bf(v.x); o.y = f2bf(v.y); o.z = f2bf(v.z); o.w = f2bf(v.w);
        reinterpret_cast<short4*>(dst)[i] = o;
    }
}

// ---------------- bf16 GEMM: C = A @ B^T (+bias) (*silu(gate)) ----------------
// A: MxK row-major bf16. Bm: NxK row-major bf16 (torch weight layout).
// C: MxN, bf16 or f32 per OUT_BF16. Optional gate (bf16, ld=ldg): C *= silu(gate).
// Tile 128x128, BK=64, 256 threads = 4 waves (2x2), each wave 64x64 (4x4 frags).
#define BM 128
#define BN 128
#define BK 64

template<int OUT_BF16, int HAS_GATE>
__global__ __launch_bounds__(256) void gemm_bt(
    const short* __restrict__ A, const short* __restrict__ Bm,
    const float* __restrict__ bias, void* __restrict__ Cv,
    int M, int N, int K,
    const short* __restrict__ gate, int ldg)
{
    __shared__ short lds_a[BM * BK];
    __shared__ short lds_b[BN * BK];

    const int tid  = threadIdx.x;
    const int lane = tid & 63;
    const int wid  = tid >> 6;
    const int wm   = wid >> 1;          // 0..1
    const int wn   = wid & 1;           // 0..1
    const int m0   = blockIdx.y * BM;
    const int n0   = blockIdx.x * BN;

    const int lrow = lane & 15;         // fragment row (A) / col (B/C)
    const int kq   = lane >> 4;         // k quarter 0..3

    f32x4 acc[4][4];
#pragma unroll
    for (int i = 0; i < 4; ++i)
#pragma unroll
        for (int j = 0; j < 4; ++j)
            acc[i][j] = (f32x4){0.f, 0.f, 0.f, 0.f};

    for (int k0 = 0; k0 < K; k0 += BK) {
        // stage A,B tiles into LDS with XOR swizzle (16B granules)
#pragma unroll
        for (int i = 0; i < 4; ++i) {
            int c = tid + i * 256;           // 0..1023
            int row = c >> 3;                // 0..127
            int col16 = c & 7;               // which 16B chunk in the row
            short8v va = *reinterpret_cast<const short8v*>(
                A + (size_t)(m0 + row) * K + k0 + col16 * 8);
            short8v vb = *reinterpret_cast<const short8v*>(
                Bm + (size_t)(n0 + row) * K + k0 + col16 * 8);
            int swa = (col16 ^ (row & 7)) * 8;
            *reinterpret_cast<short8v*>(&lds_a[row * BK + swa]) = va;
            *reinterpret_cast<short8v*>(&lds_b[row * BK + swa]) = vb;
        }
        __syncthreads();

#pragma unroll
        for (int kk = 0; kk < 2; ++kk) {
            short8v af[4], bfrag[4];
            int c16 = kk * 4 + kq;
#pragma unroll
            for (int mi = 0; mi < 4; ++mi) {
                int row = wm * 64 + mi * 16 + lrow;
                af[mi] = *reinterpret_cast<const short8v*>(
                    &lds_a[row * BK + ((c16 ^ (row & 7)) * 8)]);
            }
#pragma unroll
            for (int ni = 0; ni < 4; ++ni) {
                int row = wn * 64 + ni * 16 + lrow;
                bfrag[ni] = *reinterpret_cast<const short8v*>(
                    &lds_b[row * BK + ((c16 ^ (row & 7)) * 8)]);
            }
#pragma unroll
            for (int mi = 0; mi < 4; ++mi)
#pragma unroll
                for (int ni = 0; ni < 4; ++ni)
                    acc[mi][ni] = __builtin_amdgcn_mfma_f32_16x16x32_bf16(
                        af[mi], bfrag[ni], acc[mi][ni], 0, 0, 0);
        }
        __syncthreads();
    }

    // epilogue: C/D layout col=lane&15, row=(lane>>4)*4+reg  [verified m89/m91]
    const int lr4 = (lane >> 4) * 4;
#pragma unroll
    for (int mi = 0; mi < 4; ++mi) {
        int rowb = m0 + wm * 64 + mi * 16 + lr4;
#pragma unroll
        for (int ni = 0; ni < 4; ++ni) {
            int col = n0 + wn * 64 + ni * 16 + lrow;
            float bv = bias[col];
#pragma unroll
            for (int r = 0; r < 4; ++r) {
                int row = rowb + r;
                float val = acc[mi][ni][r] + bv;
                if (HAS_GATE) {
                    float g = bf2f(gate[(size_t)row * ldg + col]);
                    val *= g * sigf(g);
                }
                if (OUT_BF16)
                    ((short*)Cv)[(size_t)row * N + col] = f2bf(val);
                else
                    ((float*)Cv)[(size_t)row * N + col] = val;
            }
        }
    }
}

// ---------------- scan pass 1: per-chunk (A = prod oda, Bv = local h, h_init=0) ----------------
__global__ __launch_bounds__(1024) void chunk_reduce(
    const short* __restrict__ pre, float* __restrict__ sA, float* __restrict__ sBv)
{
    const int d = threadIdx.x;
    const int c = blockIdx.x;
    const int b = blockIdx.y;
    float Aacc = 1.f, Bacc = 0.f;
    size_t base = ((size_t)(b * LDIM) + c * LCHUNK) * NPROJ;
    for (int i = 0; i < LCHUNK; ++i) {
        float z  = bf2f(pre[base + d]);
        float dt = bf2f(pre[base + DDIM + d]);
        float e  = __expf(-dt);
        float r  = 1.f / (1.f + e);     // sig(dt)
        float oda = e * r;              // sig(-dt)
        float zda = sigf(z) * r;        // sig(z)*sig(dt)
        Bacc = zda + oda * Bacc;
        Aacc *= oda;
        base += NPROJ;
    }
    int idx = ((b * NCHUNK + c) << 10) + d;
    sA[idx]  = Aacc;
    sBv[idx] = Bacc;
}

// ---------------- scan pass 2: sequential prefix over chunks, record per-chunk h_init ----------------
__global__ __launch_bounds__(1024) void chunk_prefix(
    const float* __restrict__ sA, const float* __restrict__ sBv,
    const float* __restrict__ hidden, float* __restrict__ sI)
{
    const int d = threadIdx.x;
    const int b = blockIdx.x;
    float h = hidden[b * DDIM + d];
    for (int c = 0; c < NCHUNK; ++c) {
        int idx = ((b * NCHUNK + c) << 10) + d;
        sI[idx] = h;
        h = sBv[idx] + sA[idx] * h;
    }
}

// ---------------- scan pass 3: recompute with h_init; write h f32 (d_out) + bf16 (for y-GEMM) ----------------
__global__ __launch_bounds__(1024) void chunk_apply(
    const short* __restrict__ pre, const float* __restrict__ sI,
    float* __restrict__ hout, short* __restrict__ hbf)
{
    const int d = threadIdx.x;
    const int c = blockIdx.x;
    const int b = blockIdx.y;
    float h = sI[((b * NCHUNK + c) << 10) + d];
    size_t base  = ((size_t)(b * LDIM) + c * LCHUNK) * NPROJ;
    size_t obase = ((size_t)(b * LDIM) + c * LCHUNK) * DDIM + d;
    for (int i = 0; i < LCHUNK; ++i) {
        float z  = bf2f(pre[base + d]);
        float dt = bf2f(pre[base + DDIM + d]);
        float e  = __expf(-dt);
        float r  = 1.f / (1.f + e);
        float oda = e * r;
        float zda = sigf(z) * r;
        h = zda + oda * h;
        hout[obase] = h;
        hbf[obase]  = f2bf(h);
        base += NPROJ;
        obase += DDIM;
    }
}

extern "C" void kernel_launch(void* const* d_in, const int* in_sizes, int n_in,
                              void* d_out, int out_size, void* d_ws, size_t ws_size,
                              hipStream_t stream) {
    const float* x      = (const float*)d_in[0];
    const float* hidden = (const float*)d_in[1];
    const float* W_ln_z = (const float*)d_in[2];
    const float* b_ln_z = (const float*)d_in[3];
    const float* W_dt   = (const float*)d_in[4];
    const float* b_dt   = (const float*)d_in[5];
    const float* W_y    = (const float*)d_in[6];
    const float* b_y    = (const float*)d_in[7];
    const float* W_g    = (const float*)d_in[8];
    const float* b_g    = (const float*)d_in[9];

    char* ws = (char*)d_ws;
    // ws layout (bytes)
    short* x_bf   = (short*)(ws + 0);                       // 33,554,432 (reused as h_bf after proj GEMM)
    short* Wcat   = (short*)(ws + 33554432);                //  6,291,456 (W_ln_z|W_dt|W_g)
    short* Wy_bf  = (short*)(ws + 39845888);                //  2,097,152
    float* biascat= (float*)(ws + 41943040);                //     12,288
    short* pre    = (short*)(ws + 41955328);                // 100,663,296 (M x 3072 bf16)
    float* sA     = (float*)(ws + 142618624);               //  1,048,576
    float* sBv    = (float*)(ws + 143667200);               //  1,048,576
    float* sI     = (float*)(ws + 144715776);               //  1,048,576
    // total ~139 MB

    // 1) casts
    cast_f32_bf16<<<2048, 256, 0, stream>>>(x, x_bf, (MROWS * KDIM) / 4);
    cast_f32_bf16<<<1024, 256, 0, stream>>>(W_ln_z, Wcat,                (DDIM * KDIM) / 4);
    cast_f32_bf16<<<1024, 256, 0, stream>>>(W_dt,   Wcat + DDIM * KDIM,  (DDIM * KDIM) / 4);
    cast_f32_bf16<<<1024, 256, 0, stream>>>(W_g,    Wcat + 2 * DDIM * KDIM, (DDIM * KDIM) / 4);
    cast_f32_bf16<<<1024, 256, 0, stream>>>(W_y,    Wy_bf,               (DDIM * KDIM) / 4);

    // 2) concatenated bias (f32)
    hipMemcpyAsync(biascat,            b_ln_z, DDIM * sizeof(float), hipMemcpyDeviceToDevice, stream);
    hipMemcpyAsync(biascat + DDIM,     b_dt,   DDIM * sizeof(float), hipMemcpyDeviceToDevice, stream);
    hipMemcpyAsync(biascat + 2 * DDIM, b_g,    DDIM * sizeof(float), hipMemcpyDeviceToDevice, stream);

    // 3) fused projection GEMM: pre[M x 3072] = x @ [W_ln_z|W_dt|W_g]^T + bias (bf16 out)
    gemm_bt<1, 0><<<dim3(NPROJ / BN, MROWS / BM), 256, 0, stream>>>(
        x_bf, Wcat, biascat, pre, MROWS, NPROJ, KDIM, nullptr, 0);

    // 4) chunked scan -> h: f32 into d_out second half, bf16 into x_bf (reuse)
    float* y_out = (float*)d_out;
    float* h_out = (float*)d_out + (size_t)MROWS * DDIM;
    short* h_bf  = x_bf;
    chunk_reduce<<<dim3(NCHUNK, BDIM), 1024, 0, stream>>>(pre, sA, sBv);
    chunk_prefix<<<dim3(BDIM), 1024, 0, stream>>>(sA, sBv, hidden, sI);
    chunk_apply<<<dim3(NCHUNK, BDIM), 1024, 0, stream>>>(pre, sI, h_out, h_bf);

    // 5) gated output GEMM (f32 out): y = (h @ W_y^T + b_y) * silu(g_pre)
    gemm_bt<0, 1><<<dim3(DDIM / BN, MROWS / BM), 256, 0, stream>>>(
        h_bf, Wy_bf, b_y, y_out, MROWS, DDIM, KDIM, pre + 2 * DDIM, NPROJ);
}